// Round 1
// baseline (374.756 us; speedup 1.0000x reference)
//
#include <hip/hip_runtime.h>

// out[o][c] = max_{k<8} features[rules[o*8+k]][c],  C=64 floats per row.
// 16 lanes per output site, each lane owns one float4 (4 channels).
// A gathered row = 16 lanes x 16B = 256B coalesced segment.
//
// R1 experiment: 2 output sites per thread (o and o + half) -> 16 gathers
// in flight per thread before any fmax. __launch_bounds__(256,5) caps
// VGPR at 102 (est ~85 live: 64 dest + addr/rules overlap), giving
// 5 waves/SIMD x 16 loads = 80 wave-wide loads in flight per SIMD vs the
// previous 8x8=64. Tests the "latency-bound" hypothesis; if neutral, the
// kernel is memory-system-bound and dur_us is dominated by harness fills.
//
// VGPR diet: feature offsets are 32-bit byte offsets (table is 256 MB,
// fits uint) against a uniform SGPR base -> global_load saddr form.
// Streaming traffic (rules in, out out) is nontemporal so the 244 MiB
// feature table keeps the 256 MiB L3 to itself (reuse factor ~2x).

typedef int   v4i __attribute__((ext_vector_type(4)));
typedef float v4f __attribute__((ext_vector_type(4)));

__device__ __forceinline__ v4f max8(v4f v0, v4f v1, v4f v2, v4f v3,
                                    v4f v4, v4f v5, v4f v6, v4f v7) {
    v4f m;
    m.x = fmaxf(fmaxf(fmaxf(v0.x, v1.x), fmaxf(v2.x, v3.x)),
                fmaxf(fmaxf(v4.x, v5.x), fmaxf(v6.x, v7.x)));
    m.y = fmaxf(fmaxf(fmaxf(v0.y, v1.y), fmaxf(v2.y, v3.y)),
                fmaxf(fmaxf(v4.y, v5.y), fmaxf(v6.y, v7.y)));
    m.z = fmaxf(fmaxf(fmaxf(v0.z, v1.z), fmaxf(v2.z, v3.z)),
                fmaxf(fmaxf(v4.z, v5.z), fmaxf(v6.z, v7.z)));
    m.w = fmaxf(fmaxf(fmaxf(v0.w, v1.w), fmaxf(v2.w, v3.w)),
                fmaxf(fmaxf(v4.w, v5.w), fmaxf(v6.w, v7.w)));
    return m;
}

__global__ __launch_bounds__(256, 5) void maxpool_gather_kernel(
    const char* __restrict__ feat_base,  // features, byte-addressed
    const int*  __restrict__ rules,      // [N_OUT * 8]
    v4f*        __restrict__ out,        // [N_OUT * 16] float4
    int n_out, int half)
{
    int gid  = blockIdx.x * blockDim.x + threadIdx.x;
    int oA   = gid >> 4;        // first output site
    int lane = gid & 15;        // which float4 of the 16 in the row
    if (oA >= half) return;

    int oB  = oA + half;                       // second output site
    int oBc = oB < n_out ? oB : (n_out - 1);   // clamp (n_out odd tail)

    // 8+8 rule indices: 16B loads, same address across the 16 lanes of
    // each site (hardware broadcast). Nontemporal: rules are read once.
    const v4i* rA = reinterpret_cast<const v4i*>(rules + oA  * 8);
    const v4i* rB = reinterpret_cast<const v4i*>(rules + oBc * 8);
    v4i a0 = __builtin_nontemporal_load(rA);
    v4i a1 = __builtin_nontemporal_load(rA + 1);
    v4i b0 = __builtin_nontemporal_load(rB);
    v4i b1 = __builtin_nontemporal_load(rB + 1);

    unsigned lb = (unsigned)(lane << 4);           // lane * 16 bytes

    unsigned pa0 = (unsigned)a0.x * 256u + lb;
    unsigned pa1 = (unsigned)a0.y * 256u + lb;
    unsigned pa2 = (unsigned)a0.z * 256u + lb;
    unsigned pa3 = (unsigned)a0.w * 256u + lb;
    unsigned pa4 = (unsigned)a1.x * 256u + lb;
    unsigned pa5 = (unsigned)a1.y * 256u + lb;
    unsigned pa6 = (unsigned)a1.z * 256u + lb;
    unsigned pa7 = (unsigned)a1.w * 256u + lb;

    unsigned pb0 = (unsigned)b0.x * 256u + lb;
    unsigned pb1 = (unsigned)b0.y * 256u + lb;
    unsigned pb2 = (unsigned)b0.z * 256u + lb;
    unsigned pb3 = (unsigned)b0.w * 256u + lb;
    unsigned pb4 = (unsigned)b1.x * 256u + lb;
    unsigned pb5 = (unsigned)b1.y * 256u + lb;
    unsigned pb6 = (unsigned)b1.z * 256u + lb;
    unsigned pb7 = (unsigned)b1.w * 256u + lb;

    // Issue all 16 gathers before any use: 16-deep MLP per thread.
    v4f vA0 = *reinterpret_cast<const v4f*>(feat_base + pa0);
    v4f vA1 = *reinterpret_cast<const v4f*>(feat_base + pa1);
    v4f vA2 = *reinterpret_cast<const v4f*>(feat_base + pa2);
    v4f vA3 = *reinterpret_cast<const v4f*>(feat_base + pa3);
    v4f vA4 = *reinterpret_cast<const v4f*>(feat_base + pa4);
    v4f vA5 = *reinterpret_cast<const v4f*>(feat_base + pa5);
    v4f vA6 = *reinterpret_cast<const v4f*>(feat_base + pa6);
    v4f vA7 = *reinterpret_cast<const v4f*>(feat_base + pa7);

    v4f vB0 = *reinterpret_cast<const v4f*>(feat_base + pb0);
    v4f vB1 = *reinterpret_cast<const v4f*>(feat_base + pb1);
    v4f vB2 = *reinterpret_cast<const v4f*>(feat_base + pb2);
    v4f vB3 = *reinterpret_cast<const v4f*>(feat_base + pb3);
    v4f vB4 = *reinterpret_cast<const v4f*>(feat_base + pb4);
    v4f vB5 = *reinterpret_cast<const v4f*>(feat_base + pb5);
    v4f vB6 = *reinterpret_cast<const v4f*>(feat_base + pb6);
    v4f vB7 = *reinterpret_cast<const v4f*>(feat_base + pb7);

    v4f mA = max8(vA0, vA1, vA2, vA3, vA4, vA5, vA6, vA7);
    __builtin_nontemporal_store(mA, &out[(long long)oA * 16 + lane]);

    v4f mB = max8(vB0, vB1, vB2, vB3, vB4, vB5, vB6, vB7);
    if (oB < n_out)
        __builtin_nontemporal_store(mB, &out[(long long)oB * 16 + lane]);
}

extern "C" void kernel_launch(void* const* d_in, const int* in_sizes, int n_in,
                              void* d_out, int out_size, void* d_ws, size_t ws_size,
                              hipStream_t stream) {
    const char* feat  = (const char*)d_in[0];   // features [1e6, 64] f32
    const int*  rules = (const int*)d_in[1];    // rules [250000, 8] i32
    v4f*        out   = (v4f*)d_out;            // [250000, 64] f32

    const int n_out = in_sizes[1] / 8;          // 250000
    const int half  = (n_out + 1) / 2;          // sites per thread-pass
    const long long total_threads = (long long)half * 16;
    const int block = 256;
    const int grid  = (int)((total_threads + block - 1) / block);

    maxpool_gather_kernel<<<grid, block, 0, stream>>>(feat, rules, out,
                                                      n_out, half);
}